// Round 12
// baseline (24.812 us; speedup 1.0000x reference)
//
#include <hip/hip_runtime.h>

#define NJ   24
#define BLK  256
#define RPB  64                 // rows per block (= lanes per wave)
#define SDS  36                 // sD row stride in floats (4 DQ slots of 8, padded)
#define INV4PI 0.07957747154594767f
#define FOURPI 12.566370614359172f

// SE(3) element as unit quaternion + translation.
struct DQ { float w, x, y, z, t0, t1, t2; };

// readlane -> SGPR-resident constant
__device__ __forceinline__ float rdl(float v, int l) {
    return __int_as_float(__builtin_amdgcn_readlane(__float_as_int(v), l));
}

// Compose C = A * B  (rotation: A.q (x) B.q ; translation: A.t + rot(A.q, B.t))
__device__ __forceinline__ DQ dq_comp(const DQ A, const DQ B) {
    const float u10 = A.y*B.t2 - A.z*B.t1;
    const float u11 = A.z*B.t0 - A.x*B.t2;
    const float u12 = A.x*B.t1 - A.y*B.t0;
    const float u20 = A.y*u12 - A.z*u11;
    const float u21 = A.z*u10 - A.x*u12;
    const float u22 = A.x*u11 - A.y*u10;
    const float tw  = 2.0f * A.w;
    DQ C;
    C.t0 = fmaf(tw, u10, fmaf(2.0f, u20, A.t0 + B.t0));
    C.t1 = fmaf(tw, u11, fmaf(2.0f, u21, A.t1 + B.t1));
    C.t2 = fmaf(tw, u12, fmaf(2.0f, u22, A.t2 + B.t2));
    C.w = A.w*B.w - A.x*B.x - A.y*B.y - A.z*B.z;
    C.x = A.w*B.x + A.x*B.w + A.y*B.z - A.z*B.y;
    C.y = A.w*B.y - A.x*B.z + A.y*B.w + A.z*B.x;
    C.z = A.w*B.z + A.x*B.y - A.y*B.x + A.z*B.w;
    return C;
}

// exp(a*xi) from 13 scalar (SGPR) constants.
__device__ __forceinline__ DQ dq_exp(float W0, float W1, float W2, float hh,
                                     float v0, float v1, float v2,
                                     float c10, float c11, float c12,
                                     float c20, float c21, float c22,
                                     float a) {
    const float hrev = a * hh;                    // phi/(4*pi): half-angle revs
    const float sh   = __builtin_amdgcn_sinf(hrev);
    const float ch   = __builtin_amdgcn_cosf(hrev);
    const float s    = 2.0f * sh * ch;            // sin(phi)
    const float cB   = 2.0f * sh * sh;            // 1 - cos(phi)
    const float g    = fmaf(FOURPI, hrev, -s);    // phi - sin(phi)
    DQ e;
    e.w  = ch;
    e.x  = sh * W0;
    e.y  = sh * W1;
    e.z  = sh * W2;
    e.t0 = fmaf(a, v0, fmaf(cB, c10, g * c20));
    e.t1 = fmaf(a, v1, fmaf(cB, c11, g * c21));
    e.t2 = fmaf(a, v2, fmaf(cB, c12, g * c22));
    return e;
}

// ---------------------------------------------------------------------------
// Block = 4 waves, 64 rows. Wave w computes the 6-joint segment w for all 64
// rows (lane = row). Joint constants are wave-uniform: lanes 0..5 build the
// records in VGPRs; JSTEPs fetch them via v_readlane (SGPR operands, no LDS).
// Each wave writes its per-row DQ to LDS (2 b128); after the barrier wave 0
// composes the 4 segments, folds exp(M), converts Q->R, and stores; waves
// 1..3 retire early.
// ---------------------------------------------------------------------------
__global__ __launch_bounds__(BLK, 8)
void poe_main(const float* __restrict__ x,
              const float* __restrict__ eta,
              const float* __restrict__ M,
              float* __restrict__ out,
              int nBatch)
{
    __shared__ float sD[RPB * SDS];

    const int t    = threadIdx.x;
    const int lane = t & 63;
    const int w    = __builtin_amdgcn_readfirstlane(t >> 6);   // wave id 0..3

    const int row  = blockIdx.x * RPB + lane;
    const bool active = row < nBatch;

    // ---- own 6 joint angles (issue ASAP) ----
    float2 xa = make_float2(0.f,0.f), xb = xa, xc = xa;
    if (active) {
        const float2* xp = (const float2*)(x + (size_t)row * NJ + w * 6);
        xa = xp[0]; xb = xp[1]; xc = xp[2];
    }

    // ---- wave-uniform joint records: lane j (0..5) builds joint w*6+j ----
    float W0,W1,W2,hh, v0,v1,v2, c10,c11,c12, c20,c21,c22;
    {
        const int jj = w*6 + (lane < 6 ? lane : 0);
        const float e0 = eta[jj*6+0], e1 = eta[jj*6+1], e2 = eta[jj*6+2];
        const float e3 = eta[jj*6+3], e4 = eta[jj*6+4], e5 = eta[jj*6+5];
        const float k  = e0*e0 + e1*e1 + e2*e2;
        const bool  sm = (k < 1e-12f);
        const float invsqk = sm ? 0.0f : rsqrtf(k);
        const float sqk    = k * invsqk;
        const float invk   = invsqk * invsqk;
        const float invk15 = invk * invsqk;
        W0 = e0*invsqk; W1 = e1*invsqk; W2 = e2*invsqk;
        hh = sqk * INV4PI;
        v0 = e3; v1 = e4; v2 = e5;
        const float a0 = e1*e5 - e2*e4;
        const float a1 = e2*e3 - e0*e5;
        const float a2 = e0*e4 - e1*e3;
        c10 = a0*invk;  c11 = a1*invk;  c12 = a2*invk;
        c20 = (e1*a2 - e2*a1)*invk15;
        c21 = (e2*a0 - e0*a2)*invk15;
        c22 = (e0*a1 - e1*a0)*invk15;
    }

#define EXPJ(J, A_) dq_exp(rdl(W0,J), rdl(W1,J), rdl(W2,J), rdl(hh,J),       \
                           rdl(v0,J), rdl(v1,J), rdl(v2,J),                  \
                           rdl(c10,J), rdl(c11,J), rdl(c12,J),               \
                           rdl(c20,J), rdl(c21,J), rdl(c22,J), (A_))

    // ---- this wave's 6-joint partial product for its row ----
    DQ T = EXPJ(0, xa.x);
    T = dq_comp(T, EXPJ(1, xa.y));
    T = dq_comp(T, EXPJ(2, xb.x));
    T = dq_comp(T, EXPJ(3, xb.y));
    T = dq_comp(T, EXPJ(4, xc.x));
    T = dq_comp(T, EXPJ(5, xc.y));
#undef EXPJ

    // ---- publish to LDS: [lane][w], 8 floats, 16B-aligned ----
    {
        float4* dst = (float4*)(sD + lane*SDS + w*8);
        dst[0] = make_float4(T.w, T.x, T.y, T.z);
        dst[1] = make_float4(T.t0, T.t1, T.t2, 0.0f);
    }
    __syncthreads();

    if (w != 0) return;       // waves 1..3 retire; wave 0 finishes 64 rows

    // ---- exp(M) (wave 0 only, all lanes redundantly; uniform values) ----
    DQ Em;
    {
        const float m0=M[0], m1=M[1], m2=M[2], m3=M[3], m4=M[4], m5=M[5];
        const float t2 = m0*m0 + m1*m1 + m2*m2;
        const bool  sm = (t2 < 1e-12f);
        const float t2s  = sm ? 1.0f : t2;
        const float invt = rsqrtf(t2s);
        const float th   = t2s * invt;
        float s, c;
        __sincosf(th, &s, &c);
        const float invt2 = invt * invt;
        const float B = sm ? 0.5f        : (1.0f - c) * invt2;
        const float C = sm ? (1.0f/6.0f) : (th - s) * invt2 * invt;
        float sh, chh;
        __sincosf(0.5f * th, &sh, &chh);
        const float axs = sm ? 0.5f : sh * invt;   // sin(th/2)/th
        Em.w = sm ? 1.0f : chh;
        Em.x = axs * m0;  Em.y = axs * m1;  Em.z = axs * m2;
        const float a0 = m1*m5 - m2*m4, a1 = m2*m3 - m0*m5, a2 = m0*m4 - m1*m3;
        const float b0 = m1*a2 - m2*a1, b1 = m2*a0 - m0*a2, b2 = m0*a1 - m1*a0;
        Em.t0 = m3 + B*a0 + C*b0;
        Em.t1 = m4 + B*a1 + C*b1;
        Em.t2 = m5 + B*a2 + C*b2;
    }

    // ---- gather the 4 segment DQs for my row ----
    const float* src = sD + lane*SDS;
    DQ D[4];
    #pragma unroll
    for (int k = 0; k < 4; ++k) {
        const float4 qq = ((const float4*)(src + k*8))[0];
        const float4 tt = ((const float4*)(src + k*8))[1];
        D[k].w = qq.x; D[k].x = qq.y; D[k].y = qq.z; D[k].z = qq.w;
        D[k].t0 = tt.x; D[k].t1 = tt.y; D[k].t2 = tt.z;
    }

    DQ F = dq_comp(dq_comp(D[0], D[1]), dq_comp(D[2], D[3]));
    F = dq_comp(F, Em);

    // ---- Q -> R and store the full 4x4 row-major T ----
    if (active) {
        const float xx = F.x*F.x, yy = F.y*F.y, zz = F.z*F.z;
        const float xy = F.x*F.y, xz = F.x*F.z, yz = F.y*F.z;
        const float wx = F.w*F.x, wy = F.w*F.y, wz = F.w*F.z;
        float4* o = (float4*)(out + (size_t)row * 16);
        o[0] = make_float4(1.0f - 2.0f*(yy + zz), 2.0f*(xy - wz),
                           2.0f*(xz + wy),        F.t0);
        o[1] = make_float4(2.0f*(xy + wz),        1.0f - 2.0f*(xx + zz),
                           2.0f*(yz - wx),        F.t1);
        o[2] = make_float4(2.0f*(xz - wy),        2.0f*(yz + wx),
                           1.0f - 2.0f*(xx + yy), F.t2);
        o[3] = make_float4(0.0f, 0.0f, 0.0f, 1.0f);
    }
}

extern "C" void kernel_launch(void* const* d_in, const int* in_sizes, int n_in,
                              void* d_out, int out_size, void* d_ws, size_t ws_size,
                              hipStream_t stream)
{
    const float* x   = (const float*)d_in[0];
    const float* eta = (const float*)d_in[1];
    const float* M   = (const float*)d_in[2];
    float* out = (float*)d_out;

    const int nBatch = in_sizes[0] / NJ;
    const int grid   = (nBatch + RPB - 1) / RPB;

    poe_main<<<grid, BLK, 0, stream>>>(x, eta, M, out, nBatch);
}

// Round 13
// 20.642 us; speedup vs baseline: 1.2020x; 1.2020x over previous
//
#include <hip/hip_runtime.h>

#define NJ   24
#define BLK  256
#define QMF4 (NJ * 3)           // float4 index of Qm ; +1 = Pm
#define NCPY (NJ * 3 + 2)       // float4s in the LDS constant table
#define INV4PI 0.07957747154594767f
#define FOURPI 12.566370614359172f

// SE(3) element as unit quaternion + translation.
struct DQ { float w, x, y, z, t0, t1, t2; };

// Compose C = A * B  (rotation: A.q (x) B.q ; translation: A.t + rot(A.q, B.t))
__device__ __forceinline__ DQ dq_comp(const DQ A, const DQ B) {
    const float u10 = A.y*B.t2 - A.z*B.t1;
    const float u11 = A.z*B.t0 - A.x*B.t2;
    const float u12 = A.x*B.t1 - A.y*B.t0;
    const float u20 = A.y*u12 - A.z*u11;
    const float u21 = A.z*u10 - A.x*u12;
    const float u22 = A.x*u11 - A.y*u10;
    const float tw  = 2.0f * A.w;
    DQ C;
    C.t0 = fmaf(tw, u10, fmaf(2.0f, u20, A.t0 + B.t0));
    C.t1 = fmaf(tw, u11, fmaf(2.0f, u21, A.t1 + B.t1));
    C.t2 = fmaf(tw, u12, fmaf(2.0f, u22, A.t2 + B.t2));
    C.w = A.w*B.w - A.x*B.x - A.y*B.y - A.z*B.z;
    C.x = A.w*B.x + A.x*B.w + A.y*B.z - A.z*B.y;
    C.y = A.w*B.y - A.x*B.z + A.y*B.w + A.z*B.x;
    C.z = A.w*B.z + A.x*B.y - A.y*B.x + A.z*B.w;
    return C;
}

// exp(a*xi): A4=(W, hh), B4=(v, 0), C4=(c1', 0), c2' passed (W x c1').
__device__ __forceinline__ DQ dq_exp(const float4 A4, const float4 B4,
                                     const float4 C4,
                                     float c20, float c21, float c22,
                                     float a) {
    const float hrev = a * A4.w;                  // phi/(4*pi): half-angle revs
    const float sh   = __builtin_amdgcn_sinf(hrev);
    const float ch   = __builtin_amdgcn_cosf(hrev);
    const float s    = 2.0f * sh * ch;            // sin(phi)
    const float cB   = 2.0f * sh * sh;            // 1 - cos(phi)
    const float g    = fmaf(FOURPI, hrev, -s);    // phi - sin(phi)
    DQ e;
    e.w  = ch;
    e.x  = sh * A4.x;
    e.y  = sh * A4.y;
    e.z  = sh * A4.z;
    e.t0 = fmaf(a, B4.x, fmaf(cB, C4.x, g * c20));
    e.t1 = fmaf(a, B4.y, fmaf(cB, C4.y, g * c21));
    e.t2 = fmaf(a, B4.z, fmaf(cB, C4.z, g * c22));
    return e;
}

// Two __shfl_xor combine rounds across the quad (q = lane&3).
__device__ __forceinline__ DQ quad_combine(DQ T, const int q) {
    #pragma unroll
    for (int bit = 1; bit <= 2; bit <<= 1) {
        DQ O;
        O.w  = __shfl_xor(T.w,  bit);  O.x  = __shfl_xor(T.x,  bit);
        O.y  = __shfl_xor(T.y,  bit);  O.z  = __shfl_xor(T.z,  bit);
        O.t0 = __shfl_xor(T.t0, bit);  O.t1 = __shfl_xor(T.t1, bit);
        O.t2 = __shfl_xor(T.t2, bit);
        const bool up = (q & bit) != 0;     // self is the SECOND factor
        DQ A, B;
        A.w  = up ? O.w  : T.w;   B.w  = up ? T.w  : O.w;
        A.x  = up ? O.x  : T.x;   B.x  = up ? T.x  : O.x;
        A.y  = up ? O.y  : T.y;   B.y  = up ? T.y  : O.y;
        A.z  = up ? O.z  : T.z;   B.z  = up ? T.z  : O.z;
        A.t0 = up ? O.t0 : T.t0;  B.t0 = up ? T.t0 : O.t0;
        A.t1 = up ? O.t1 : T.t1;  B.t1 = up ? T.t1 : O.t1;
        A.t2 = up ? O.t2 : T.t2;  B.t2 = up ? T.t2 : O.t2;
        T = dq_comp(A, B);
    }
    return T;
}

// Q -> R, pick row q of [R|t; 0 1].
__device__ __forceinline__ float4 row_of(const DQ F, const int q) {
    const float xx = F.x*F.x, yy = F.y*F.y, zz = F.z*F.z;
    const float xy = F.x*F.y, xz = F.x*F.z, yz = F.y*F.z;
    const float wx = F.w*F.x, wy = F.w*F.y, wz = F.w*F.z;
    float4 r;
    if      (q == 0) r = make_float4(1.0f-2.0f*(yy+zz), 2.0f*(xy-wz), 2.0f*(xz+wy), F.t0);
    else if (q == 1) r = make_float4(2.0f*(xy+wz), 1.0f-2.0f*(xx+zz), 2.0f*(yz-wx), F.t1);
    else if (q == 2) r = make_float4(2.0f*(xz-wy), 2.0f*(yz+wx), 1.0f-2.0f*(xx+yy), F.t2);
    else             r = make_float4(0.0f, 0.0f, 0.0f, 1.0f);
    return r;
}

// ---------------------------------------------------------------------------
// Fused kernel, 2 rows per thread, 4 lanes per row.
// Prep: threads 0..23 build 3-float4 joint records in LDS (c2' derived at use
// via c2' = W x c1', shared across the thread's two rows); thread 24 builds
// exp(M). Lane q of a quad owns joints 6q..6q+5 for BOTH rows (r0 = 2*quad,
// r1 = r0+1): per joint one record load feeds two chain steps (independent
// streams -> ILP). Then each row: 2 shfl_xor combine rounds, fold exp(M),
// Q->R, one 16B store per lane per row (coalesced).
// ---------------------------------------------------------------------------
__global__ __launch_bounds__(BLK, 4)
void poe_main(const float* __restrict__ x,
              const float* __restrict__ eta,
              const float* __restrict__ M,
              float* __restrict__ out,
              int nBatch)
{
    __shared__ float4 sC[NCPY];
    float* sF = (float*)sC;

    const int t = threadIdx.x;
    if (t < NJ) {
        const float w0 = eta[t*6+0], w1 = eta[t*6+1], w2 = eta[t*6+2];
        const float v0 = eta[t*6+3], v1 = eta[t*6+4], v2 = eta[t*6+5];
        const float k  = w0*w0 + w1*w1 + w2*w2;
        const bool  sm = (k < 1e-12f);
        const float invsqk = sm ? 0.0f : rsqrtf(k);
        const float sqk    = k * invsqk;
        const float invk   = invsqk * invsqk;
        float* r = sF + t * 12;
        r[0]  = w0*invsqk;        r[1]  = w1*invsqk;
        r[2]  = w2*invsqk;        r[3]  = sqk * INV4PI;
        r[4]  = v0;  r[5]  = v1;  r[6]  = v2;  r[7] = 0.0f;
        r[8]  = (w1*v2 - w2*v1)*invk;
        r[9]  = (w2*v0 - w0*v2)*invk;
        r[10] = (w0*v1 - w1*v0)*invk;
        r[11] = 0.0f;
    } else if (t == NJ) {
        const float w0 = M[0], w1 = M[1], w2 = M[2];
        const float v0 = M[3], v1 = M[4], v2 = M[5];
        const float t2 = w0*w0 + w1*w1 + w2*w2;
        const bool  sm = (t2 < 1e-12f);
        const float t2s  = sm ? 1.0f : t2;
        const float invt = rsqrtf(t2s);
        const float th   = t2s * invt;
        float s, c;
        __sincosf(th, &s, &c);
        const float invt2 = invt * invt;
        const float B = sm ? 0.5f        : (1.0f - c) * invt2;
        const float C = sm ? (1.0f/6.0f) : (th - s) * invt2 * invt;
        float sh, chh;
        __sincosf(0.5f * th, &sh, &chh);
        const float axs = sm ? 0.5f : sh * invt;   // sin(th/2)/th
        float* r = sF + QMF4 * 4;
        r[0] = sm ? 1.0f : chh;
        r[1] = axs * w0;  r[2] = axs * w1;  r[3] = axs * w2;
        const float a0 = w1*v2 - w2*v1, a1 = w2*v0 - w0*v2, a2 = w0*v1 - w1*v0;
        const float b0 = w1*a2 - w2*a1, b1 = w2*a0 - w0*a2, b2 = w0*a1 - w1*a0;
        r[4] = v0 + B*a0 + C*b0;
        r[5] = v1 + B*a1 + C*b1;
        r[6] = v2 + B*a2 + C*b2;
        r[7] = 0.0f;
    }

    // ---- two rows per thread ----
    const int gid  = blockIdx.x * BLK + t;
    const int quad = gid >> 2;
    const int q    = gid & 3;
    const int r0   = quad * 2;
    const int r1   = r0 + 1;
    const bool a0  = r0 < nBatch;
    const bool a1  = r1 < nBatch;

    float2 xa0 = make_float2(0.f,0.f), xb0 = xa0, xc0 = xa0;
    float2 xa1 = xa0, xb1 = xa0, xc1 = xa0;
    if (a0) {
        const float2* xp = (const float2*)(x + (size_t)r0 * NJ + q * 6);
        xa0 = xp[0]; xb0 = xp[1]; xc0 = xp[2];
    }
    if (a1) {
        const float2* xp = (const float2*)(x + (size_t)r1 * NJ + q * 6);
        xa1 = xp[0]; xb1 = xp[1]; xc1 = xp[2];
    }

    __syncthreads();

    const int cbase = q * 18;   // float4 index of this lane's first record
    DQ TA, TB;

#define JSTEP(JJ, A0_, A1_, FIRST) do {                                       \
    const float4 A4 = sC[cbase + (JJ)*3 + 0];                                 \
    const float4 B4 = sC[cbase + (JJ)*3 + 1];                                 \
    const float4 C4 = sC[cbase + (JJ)*3 + 2];                                 \
    const float c20 = A4.y*C4.z - A4.z*C4.y;   /* c2' = W x c1' */            \
    const float c21 = A4.z*C4.x - A4.x*C4.z;                                  \
    const float c22 = A4.x*C4.y - A4.y*C4.x;                                  \
    const DQ eA = dq_exp(A4, B4, C4, c20, c21, c22, (A0_));                   \
    const DQ eB = dq_exp(A4, B4, C4, c20, c21, c22, (A1_));                   \
    if (FIRST) { TA = eA; TB = eB; }                                          \
    else       { TA = dq_comp(TA, eA); TB = dq_comp(TB, eB); }                \
} while (0)

    JSTEP(0, xa0.x, xa1.x, true);
    JSTEP(1, xa0.y, xa1.y, false);
    JSTEP(2, xb0.x, xb1.x, false);
    JSTEP(3, xb0.y, xb1.y, false);
    JSTEP(4, xc0.x, xc1.x, false);
    JSTEP(5, xc0.y, xc1.y, false);
#undef JSTEP

    // ---- combine across the quad (both rows) ----
    TA = quad_combine(TA, q);
    TB = quad_combine(TB, q);

    // ---- fold exp(M) ----
    DQ Em;
    {
        const float4 Qm = sC[QMF4];
        const float4 Pm = sC[QMF4 + 1];
        Em.w = Qm.x; Em.x = Qm.y; Em.y = Qm.z; Em.z = Qm.w;
        Em.t0 = Pm.x; Em.t1 = Pm.y; Em.t2 = Pm.z;
    }
    TA = dq_comp(TA, Em);
    TB = dq_comp(TB, Em);

    // ---- stores: one 16B row per lane per batch-row (coalesced) ----
    if (a0) ((float4*)out)[(size_t)r0 * 4 + q] = row_of(TA, q);
    if (a1) ((float4*)out)[(size_t)r1 * 4 + q] = row_of(TB, q);
}

extern "C" void kernel_launch(void* const* d_in, const int* in_sizes, int n_in,
                              void* d_out, int out_size, void* d_ws, size_t ws_size,
                              hipStream_t stream)
{
    const float* x   = (const float*)d_in[0];
    const float* eta = (const float*)d_in[1];
    const float* M   = (const float*)d_in[2];
    float* out = (float*)d_out;

    const int nBatch   = in_sizes[0] / NJ;
    const int nQuads   = (nBatch + 1) / 2;        // one quad per 2 rows
    const int nThreads = nQuads * 4;
    const int grid     = (nThreads + BLK - 1) / BLK;

    poe_main<<<grid, BLK, 0, stream>>>(x, eta, M, out, nBatch);
}